// Round 1
// baseline (3892.227 us; speedup 1.0000x reference)
//
#include <hip/hip_runtime.h>

typedef unsigned short u16;
typedef unsigned int   u32;
typedef __bf16  bf16x8  __attribute__((ext_vector_type(8)));
typedef float   floatx4 __attribute__((ext_vector_type(4)));

static constexpr int VV = 32000, EE = 1024, LL = 4, HH = 16, HSZ = 64;
static constexpr int BB = 4, TT = 1024, MR = BB * TT;   // MR = 4096 token rows

#define DEVFN __device__ __forceinline__

DEVFN float bf2f(u16 u) { u32 v = (u32)u << 16; return __uint_as_float(v); }
DEVFN u16 f2bf(float f) {
    u32 u = __float_as_uint(f);
    u32 r = (u + 0x7FFFu + ((u >> 16) & 1u)) >> 16;   // round-to-nearest-even
    return (u16)r;
}
DEVFN u16 to_bf(float v) { return f2bf(v); }
DEVFN u16 to_bf(u16 v)   { return v; }

DEVFN float wred_sum(float v) {
#pragma unroll
    for (int m = 32; m >= 1; m >>= 1) v += __shfl_xor(v, m, 64);
    return v;
}
DEVFN float wred_max(float v) {
#pragma unroll
    for (int m = 32; m >= 1; m >>= 1) v = fmaxf(v, __shfl_xor(v, m, 64));
    return v;
}

// ---------------- transpose + (optional f32->bf16) convert ----------------
// in: [R][C] (ldin), viewed at offset zb*inZb + zh*inZh ; out: [C][R] at z*outZ (bf16)
template <typename TIN>
__global__ __launch_bounds__(256) void k_transpose(
    const TIN* __restrict__ in, int ldin, u16* __restrict__ out,
    int R, int C, int ZH, long inZb, long inZh, long outZ)
{
    __shared__ TIN tile[32][33];
    int z = blockIdx.z, zb = z / ZH, zh = z - zb * ZH;
    in  += (long)zb * inZb + (long)zh * inZh;
    out += (long)z * outZ;
    int c0 = blockIdx.x * 32, r0 = blockIdx.y * 32;
    int lx = threadIdx.x & 31, ly = threadIdx.x >> 5;
#pragma unroll
    for (int i = 0; i < 4; i++)
        tile[ly + i * 8][lx] = in[(long)(r0 + ly + i * 8) * ldin + c0 + lx];
    __syncthreads();
#pragma unroll
    for (int i = 0; i < 4; i++)
        out[(long)(c0 + ly + i * 8) * R + r0 + lx] = to_bf(tile[lx][ly + i * 8]);
}

// ---------------- embedding ----------------
__global__ __launch_bounds__(256) void k_embed(
    const int* __restrict__ idx, const float* __restrict__ tok,
    const float* __restrict__ pos, float* __restrict__ x)
{
    int row = blockIdx.x;
    int e = threadIdx.x * 4;
    int id = idx[row];
    int t = row & (TT - 1);
    float4 a = *(const float4*)(tok + (long)id * EE + e);
    float4 p = *(const float4*)(pos + (long)t * EE + e);
    float4 o;
    o.x = a.x + p.x; o.y = a.y + p.y; o.z = a.z + p.z; o.w = a.w + p.w;
    *(float4*)(x + (long)row * EE + e) = o;
}

// ---------------- layernorm (f32 in, bf16 out) ----------------
__global__ __launch_bounds__(256) void k_ln(
    const float* __restrict__ x, const float* __restrict__ g,
    const float* __restrict__ b, u16* __restrict__ h)
{
    __shared__ float red[8];
    int row = blockIdx.x, tid = threadIdx.x;
    const float* xr = x + (long)row * EE;
    float4 v = *(const float4*)(xr + tid * 4);
    float s1 = v.x + v.y + v.z + v.w;
    float s2 = v.x * v.x + v.y * v.y + v.z * v.z + v.w * v.w;
    s1 = wred_sum(s1); s2 = wred_sum(s2);
    int wid = tid >> 6;
    if ((tid & 63) == 0) { red[wid * 2] = s1; red[wid * 2 + 1] = s2; }
    __syncthreads();
    float t1 = red[0] + red[2] + red[4] + red[6];
    float t2 = red[1] + red[3] + red[5] + red[7];
    float mu = t1 * (1.f / EE);
    float var = t2 * (1.f / EE) - mu * mu;
    float rs = rsqrtf(var + 1e-5f);
    int e = tid * 4;
    float4 gv = *(const float4*)(g + e);
    float4 bv = *(const float4*)(b + e);
    u32 p0 = (u32)f2bf((v.x - mu) * rs * gv.x + bv.x) | ((u32)f2bf((v.y - mu) * rs * gv.y + bv.y) << 16);
    u32 p1 = (u32)f2bf((v.z - mu) * rs * gv.z + bv.z) | ((u32)f2bf((v.w - mu) * rs * gv.w + bv.w) << 16);
    uint2 pk; pk.x = p0; pk.y = p1;
    *(uint2*)(h + (long)row * EE + e) = pk;
}

// ---------------- GEMM: C = A(bf16,[M][K]) x Bt(bf16,[N][K])^T ----------------
// EPI: 0 bf16 plain | 1 bf16 * scale | 2 f32 in-place resid += acc+bias
//      3 bf16 relu(acc+bias)         | 4 f32 acc+bias
template <int EPI>
__global__ __launch_bounds__(256) void k_gemm(
    const u16* __restrict__ A, int lda, long sAzb, long sAzh,
    const u16* __restrict__ Bt, int ldb, long sBzb, long sBzh,
    void* __restrict__ Cv, int ldc, long sCzb, long sCzh,
    const float* __restrict__ bias,
    int Mdim, int Ndim, int Kdim, int ZH, float scale, int causal)
{
    int bm = blockIdx.x, bn = blockIdx.y;
    if (causal && bn > bm) return;
    int z = blockIdx.z, zb = z / ZH, zh = z - zb * ZH;
    A  += (long)zb * sAzb + (long)zh * sAzh;
    Bt += (long)zb * sBzb + (long)zh * sBzh;

    __shared__ u16 As[128][40];   // +8 pad: 80B row stride -> 2-way bank alias (free)
    __shared__ u16 Bs[128][40];

    int tid = threadIdx.x;
    int lane = tid & 63, wid = tid >> 6;
    int wr = wid >> 1, wc = wid & 1;
    int lr = lane & 15, lk = (lane >> 4) << 3;
    int sr = tid >> 2, skc = (tid & 3) << 3;

    floatx4 acc[4][4];
    floatx4 zf = {0.f, 0.f, 0.f, 0.f};
#pragma unroll
    for (int m = 0; m < 4; m++)
#pragma unroll
        for (int n = 0; n < 4; n++) acc[m][n] = zf;
    uint4 zero4 = {0u, 0u, 0u, 0u};

    for (int kt = 0; kt < Kdim; kt += 32) {
        __syncthreads();
        {
            const u16* a0 = A + (long)(bm * 128 + sr) * lda + kt + skc;
            *(uint4*)&As[sr][skc]      = *(const uint4*)a0;
            *(uint4*)&As[sr + 64][skc] = *(const uint4*)(a0 + (long)64 * lda);
            int n0 = bn * 128 + sr, n1 = n0 + 64;
            const u16* b0 = Bt + (long)n0 * ldb + kt + skc;
            *(uint4*)&Bs[sr][skc]      = (n0 < Ndim) ? *(const uint4*)b0 : zero4;
            *(uint4*)&Bs[sr + 64][skc] = (n1 < Ndim) ? *(const uint4*)(b0 + (long)64 * ldb) : zero4;
        }
        __syncthreads();
        bf16x8 af[4], bfr[4];
#pragma unroll
        for (int m = 0; m < 4; m++)
            af[m] = *reinterpret_cast<const bf16x8*>(&As[wr * 64 + m * 16 + lr][lk]);
#pragma unroll
        for (int n = 0; n < 4; n++)
            bfr[n] = *reinterpret_cast<const bf16x8*>(&Bs[wc * 64 + n * 16 + lr][lk]);
#pragma unroll
        for (int m = 0; m < 4; m++)
#pragma unroll
            for (int n = 0; n < 4; n++)
                acc[m][n] = __builtin_amdgcn_mfma_f32_16x16x32_bf16(af[m], bfr[n], acc[m][n], 0, 0, 0);
    }

    long coff = (long)zb * sCzb + (long)zh * sCzh;
    int r0 = bm * 128 + wr * 64, c0 = bn * 128 + wc * 64;
    int ri = (lane >> 4) << 2;
#pragma unroll
    for (int n = 0; n < 4; n++) {
        int colg = c0 + n * 16 + lr;
        if (colg >= Ndim) continue;
        float bv = 0.f;
        if constexpr (EPI == 2 || EPI == 3 || EPI == 4) bv = bias[colg];
#pragma unroll
        for (int m = 0; m < 4; m++) {
#pragma unroll
            for (int i = 0; i < 4; i++) {
                int rowg = r0 + m * 16 + ri + i;
                long cidx = coff + (long)rowg * ldc + colg;
                float v = acc[m][n][i];
                if constexpr (EPI == 0) ((u16*)Cv)[cidx] = f2bf(v);
                else if constexpr (EPI == 1) ((u16*)Cv)[cidx] = f2bf(v * scale);
                else if constexpr (EPI == 2) { float* Cf = (float*)Cv; Cf[cidx] = Cf[cidx] + v + bv; }
                else if constexpr (EPI == 3) ((u16*)Cv)[cidx] = f2bf(fmaxf(v + bv, 0.f));
                else { float* Cf = (float*)Cv; Cf[cidx] = v + bv; }
            }
        }
    }
}

// ---------------- causal softmax, in-place over bf16 scores [Z][T][T] ----------------
__global__ __launch_bounds__(256) void k_softmax(u16* __restrict__ sc)
{
    __shared__ float red[4];
    long blk = blockIdx.x;              // z*T + q
    u16* rowp = sc + blk * (long)TT;
    int q = (int)(blk & (TT - 1));
    int tid = threadIdx.x, j0 = tid * 4;
    uint2 uv = *(const uint2*)(rowp + j0);
    float f0 = bf2f((u16)(uv.x & 0xFFFF)), f1 = bf2f((u16)(uv.x >> 16));
    float f2 = bf2f((u16)(uv.y & 0xFFFF)), f3 = bf2f((u16)(uv.y >> 16));
    bool k0 = (j0 + 0) <= q, k1 = (j0 + 1) <= q, k2 = (j0 + 2) <= q, k3 = (j0 + 3) <= q;
    float m = -3.0e38f;
    if (k0) m = fmaxf(m, f0);
    if (k1) m = fmaxf(m, f1);
    if (k2) m = fmaxf(m, f2);
    if (k3) m = fmaxf(m, f3);
    m = wred_max(m);
    if ((tid & 63) == 0) red[tid >> 6] = m;
    __syncthreads();
    m = fmaxf(fmaxf(red[0], red[1]), fmaxf(red[2], red[3]));
    float p0 = k0 ? __expf(f0 - m) : 0.f;
    float p1 = k1 ? __expf(f1 - m) : 0.f;
    float p2 = k2 ? __expf(f2 - m) : 0.f;
    float p3 = k3 ? __expf(f3 - m) : 0.f;
    float s = p0 + p1 + p2 + p3;
    s = wred_sum(s);
    __syncthreads();
    if ((tid & 63) == 0) red[tid >> 6] = s;
    __syncthreads();
    s = red[0] + red[1] + red[2] + red[3];
    float inv = 1.f / s;
    uint2 op;
    op.x = (u32)f2bf(p0 * inv) | ((u32)f2bf(p1 * inv) << 16);
    op.y = (u32)f2bf(p2 * inv) | ((u32)f2bf(p3 * inv) << 16);
    *(uint2*)(rowp + j0) = op;
}

// ---------------- loss: per-row online logsumexp + NLL ----------------
__global__ __launch_bounds__(256) void k_loss_row(
    const float* __restrict__ logits, const int* __restrict__ tgt, float* __restrict__ rl)
{
    __shared__ float2 wred[4];
    int row = blockIdx.x;
    const float* p = logits + (long)row * VV;
    float m = -3.0e38f, s = 0.f;
    for (int j = threadIdx.x; j < VV; j += 256) {
        float v = p[j];
        if (v > m) { s = s * __expf(m - v); m = v; }
        s += __expf(v - m);
    }
#pragma unroll
    for (int off = 32; off >= 1; off >>= 1) {
        float om = __shfl_xor(m, off, 64), os = __shfl_xor(s, off, 64);
        float nm = fmaxf(m, om);
        s = s * __expf(m - nm) + os * __expf(om - nm);
        m = nm;
    }
    if ((threadIdx.x & 63) == 0) wred[threadIdx.x >> 6] = make_float2(m, s);
    __syncthreads();
    if (threadIdx.x == 0) {
        float M = wred[0].x, Sv = wred[0].y;
#pragma unroll
        for (int i = 1; i < 4; i++) {
            float nm = fmaxf(M, wred[i].x);
            Sv = Sv * __expf(M - nm) + wred[i].y * __expf(wred[i].x - nm);
            M = nm;
        }
        float lse = M + logf(Sv);
        rl[row] = lse - p[tgt[row]];
    }
}

__global__ __launch_bounds__(256) void k_loss_final(const float* __restrict__ rl, float* __restrict__ out)
{
    __shared__ float red[4];
    float s = 0.f;
    for (int j = threadIdx.x; j < MR; j += 256) s += rl[j];
    s = wred_sum(s);
    if ((threadIdx.x & 63) == 0) red[threadIdx.x >> 6] = s;
    __syncthreads();
    if (threadIdx.x == 0) out[0] = (red[0] + red[1] + red[2] + red[3]) * (1.f / MR);
}

// ---------------- host ----------------
extern "C" void kernel_launch(void* const* d_in, const int* in_sizes, int n_in,
                              void* d_out, int out_size, void* d_ws, size_t ws_size,
                              hipStream_t stream)
{
    const int*   idx   = (const int*)  d_in[0];
    const int*   tgt   = (const int*)  d_in[1];
    const float* tok   = (const float*)d_in[2];
    const float* pos   = (const float*)d_in[3];
    const float* Wq    = (const float*)d_in[4];
    const float* Wk    = (const float*)d_in[5];
    const float* Wv    = (const float*)d_in[6];
    const float* Wp    = (const float*)d_in[7];
    const float* bproj = (const float*)d_in[8];
    const float* ln1g  = (const float*)d_in[9];
    const float* ln1b  = (const float*)d_in[10];
    const float* ln2g  = (const float*)d_in[11];
    const float* ln2b  = (const float*)d_in[12];
    const float* W1    = (const float*)d_in[13];
    const float* b1    = (const float*)d_in[14];
    const float* W2    = (const float*)d_in[15];
    const float* b2    = (const float*)d_in[16];
    const float* lnfg  = (const float*)d_in[17];
    const float* lnfb  = (const float*)d_in[18];
    const float* Wlm   = (const float*)d_in[19];
    const float* blm   = (const float*)d_in[20];

    char* wp = (char*)d_ws;
    auto alloc = [&](size_t bytes) { char* p = wp; wp += (bytes + 255) & ~(size_t)255; return p; };
    u16*   WqT  = (u16*)  alloc((size_t)LL * EE * EE * 2);
    u16*   WkT  = (u16*)  alloc((size_t)LL * EE * EE * 2);
    u16*   WvT  = (u16*)  alloc((size_t)LL * EE * EE * 2);
    u16*   WpT  = (u16*)  alloc((size_t)LL * EE * EE * 2);
    u16*   W1T  = (u16*)  alloc((size_t)LL * EE * 4 * EE * 2);
    u16*   W2T  = (u16*)  alloc((size_t)LL * 4 * EE * EE * 2);
    u16*   WlmT = (u16*)  alloc((size_t)VV * EE * 2);
    float* x    = (float*)alloc((size_t)MR * EE * 4);
    u16*   h    = (u16*)  alloc((size_t)MR * EE * 2);
    u16*   qb   = (u16*)  alloc((size_t)MR * EE * 2);
    u16*   kb   = (u16*)  alloc((size_t)MR * EE * 2);
    u16*   vb   = (u16*)  alloc((size_t)MR * EE * 2);
    u16*   vt   = (u16*)  alloc((size_t)BB * HH * HSZ * TT * 2);
    u16*   sc   = (u16*)  alloc((size_t)BB * HH * TT * TT * 2);
    u16*   ob   = (u16*)  alloc((size_t)MR * EE * 2);
    u16*   mid  = (u16*)  alloc((size_t)MR * 4 * EE * 2);
    float* rl   = (float*)alloc((size_t)MR * 4);

    float* logits = (float*)d_out;
    float* loss   = logits + (size_t)MR * VV;

    // --- weight prep: transpose + bf16 convert ---
    k_transpose<float><<<dim3(EE / 32, EE / 32, LL), 256, 0, stream>>>(Wq, EE, WqT, EE, EE, 1, (long)EE * EE, 0, (long)EE * EE);
    k_transpose<float><<<dim3(EE / 32, EE / 32, LL), 256, 0, stream>>>(Wk, EE, WkT, EE, EE, 1, (long)EE * EE, 0, (long)EE * EE);
    k_transpose<float><<<dim3(EE / 32, EE / 32, LL), 256, 0, stream>>>(Wv, EE, WvT, EE, EE, 1, (long)EE * EE, 0, (long)EE * EE);
    k_transpose<float><<<dim3(EE / 32, EE / 32, LL), 256, 0, stream>>>(Wp, EE, WpT, EE, EE, 1, (long)EE * EE, 0, (long)EE * EE);
    k_transpose<float><<<dim3(4 * EE / 32, EE / 32, LL), 256, 0, stream>>>(W1, 4 * EE, W1T, EE, 4 * EE, 1, (long)EE * 4 * EE, 0, (long)EE * 4 * EE);
    k_transpose<float><<<dim3(EE / 32, 4 * EE / 32, LL), 256, 0, stream>>>(W2, EE, W2T, 4 * EE, EE, 1, (long)4 * EE * EE, 0, (long)4 * EE * EE);
    k_transpose<float><<<dim3(VV / 32, EE / 32, 1), 256, 0, stream>>>(Wlm, VV, WlmT, EE, VV, 1, 0, 0, 0);

    k_embed<<<MR, 256, 0, stream>>>(idx, tok, pos, x);

    for (int l = 0; l < LL; l++) {
        k_ln<<<MR, 256, 0, stream>>>(x, ln1g + l * EE, ln1b + l * EE, h);
        k_gemm<0><<<dim3(MR / 128, EE / 128, 1), 256, 0, stream>>>(
            h, EE, 0, 0, WqT + (size_t)l * EE * EE, EE, 0, 0, qb, EE, 0, 0,
            nullptr, MR, EE, EE, 1, 1.f, 0);
        k_gemm<0><<<dim3(MR / 128, EE / 128, 1), 256, 0, stream>>>(
            h, EE, 0, 0, WkT + (size_t)l * EE * EE, EE, 0, 0, kb, EE, 0, 0,
            nullptr, MR, EE, EE, 1, 1.f, 0);
        k_gemm<0><<<dim3(MR / 128, EE / 128, 1), 256, 0, stream>>>(
            h, EE, 0, 0, WvT + (size_t)l * EE * EE, EE, 0, 0, vb, EE, 0, 0,
            nullptr, MR, EE, EE, 1, 1.f, 0);
        k_transpose<u16><<<dim3(HSZ / 32, TT / 32, BB * HH), 256, 0, stream>>>(
            vb, EE, vt, TT, HSZ, HH, (long)TT * EE, (long)HSZ, (long)HSZ * TT);
        // scores = scale * Q Kt  (causal blocks skipped)
        k_gemm<1><<<dim3(TT / 128, TT / 128, BB * HH), 256, 0, stream>>>(
            qb, EE, (long)TT * EE, (long)HSZ, kb, EE, (long)TT * EE, (long)HSZ,
            sc, TT, (long)HH * TT * TT, (long)TT * TT,
            nullptr, TT, TT, HSZ, HH, 0.125f, 1);
        k_softmax<<<BB * HH * TT, 256, 0, stream>>>(sc);
        // O = P V   (Bt = per-head V^T)
        k_gemm<0><<<dim3(TT / 128, 1, BB * HH), 256, 0, stream>>>(
            sc, TT, (long)HH * TT * TT, (long)TT * TT, vt, TT, (long)HH * HSZ * TT, (long)HSZ * TT,
            ob, EE, (long)TT * EE, (long)HSZ,
            nullptr, TT, HSZ, TT, HH, 1.f, 0);
        k_gemm<2><<<dim3(MR / 128, EE / 128, 1), 256, 0, stream>>>(
            ob, EE, 0, 0, WpT + (size_t)l * EE * EE, EE, 0, 0, x, EE, 0, 0,
            bproj + l * EE, MR, EE, EE, 1, 1.f, 0);
        k_ln<<<MR, 256, 0, stream>>>(x, ln2g + l * EE, ln2b + l * EE, h);
        k_gemm<3><<<dim3(MR / 128, 4 * EE / 128, 1), 256, 0, stream>>>(
            h, EE, 0, 0, W1T + (size_t)l * 4 * EE * EE, EE, 0, 0, mid, 4 * EE, 0, 0,
            b1 + l * 4 * EE, MR, 4 * EE, EE, 1, 1.f, 0);
        k_gemm<2><<<dim3(MR / 128, EE / 128, 1), 256, 0, stream>>>(
            mid, 4 * EE, 0, 0, W2T + (size_t)l * 4 * EE * EE, 4 * EE, 0, 0, x, EE, 0, 0,
            b2 + l * EE, MR, EE, 4 * EE, 1, 1.f, 0);
    }

    k_ln<<<MR, 256, 0, stream>>>(x, lnfg, lnfb, h);
    k_gemm<4><<<dim3(MR / 128, VV / 128, 1), 256, 0, stream>>>(
        h, EE, 0, 0, WlmT, EE, 0, 0, logits, VV, 0, 0,
        blm, MR, VV, EE, 1, 1.f, 0);

    k_loss_row<<<MR, 256, 0, stream>>>(logits, tgt, rl);
    k_loss_final<<<1, 256, 0, stream>>>(rl, loss);
}